// Round 2
// baseline (738.007 us; speedup 1.0000x reference)
//
#include <hip/hip_runtime.h>
#include <stdint.h>

// ---------------------------------------------------------------------------
// Phased reformulation.
//   Phase 1: hidden raster S (sequential, w1-STDP with clip, per-column waves)
//   Phase 2: bit-pack S;  G = S S^T via popcount (exact integers)
//   Phase 3: M_T(tau,t') = nu2*(H - K) from G via prefix/suffix decay scans
//   Phase 4: A_T = (S @ w2_0)^T  f32 tiled GEMM
//   Phase 5: sequential output LIF: i(t) = A(t,j) + sum_{tau<t} M(t,tau) so(tau)
//            rank-1 running update per step, no reductions, no p+/p- traces.
// Valid because w2 is NOT clipped (only w1 is) -> w2 evolution is linear.
// ---------------------------------------------------------------------------

#define DECAY_V  0.90483741803595952f   // exp(-1/10)
#define DECAY_TR 0.95122942450071403f   // exp(-1/20)
#define DECAY_PM 0.95122942450071403f   // exp(-1/20)
#define REST_F   (-70.0f)
#define RESET_F  (-65.0f)
#define THRESH_F (-55.0f)
#define ALPHA_F  (0.95f)
#define BETA_F   (0.8f)
#define NU1_PRE_F  (0.001f)
#define NU1_POST_F (0.01f)
#define NU2_F      (0.0001f)
#define GAIN_F     (20.0f)

static constexpr int IN_D  = 544;
static constexpr int HID_D = 1024;
static constexpr int OUT_D = 2048;
static constexpr int TMAX  = 512;      // supports T <= 512 (harness T = 500)
static constexpr int NW    = TMAX / 64; // 8 chunk words

// ------------------------- Phase 1: hidden raster --------------------------
__global__ __launch_bounds__(256, 2)
void hidden_kernel(const float* __restrict__ x, const float* __restrict__ w1,
                   const int* __restrict__ Tp, float* __restrict__ Sf)
{
    const int T = Tp[0];
    const int p = blockIdx.x;                 // 0..255, hidden cols 4p..4p+3
    const int tid = threadIdx.x, lane = tid & 63, wv = tid >> 6;
    const int col = p * 4 + wv;
    __shared__ float sh4[2][4];

    float w[9], v_in[9], tr_in[9], rate[9];
    #pragma unroll
    for (int k = 0; k < 9; ++k) {
        const int i = lane + 64 * k;
        const bool ok = (i < IN_D);
        w[k]     = ok ? w1[(size_t)i * HID_D + col] : 0.f;
        rate[k]  = ok ? x[i] * GAIN_F : 0.f;
        v_in[k]  = REST_F;
        tr_in[k] = 0.f;
    }
    float v_h = 0.f, b_h = 0.f, tr_h = 0.f;

    for (int t = 0; t < T; ++t) {
        float acc = 0.f, s_in[9];
        #pragma unroll
        for (int k = 0; k < 9; ++k) {
            const float vv = DECAY_V * (v_in[k] - REST_F) + REST_F + rate[k];
            const bool sp = (vv >= THRESH_F);
            const float s = sp ? 1.f : 0.f;
            v_in[k]  = sp ? RESET_F : vv;
            tr_in[k] = sp ? 1.f : tr_in[k] * DECAY_TR;
            s_in[k]  = s;
            acc = fmaf(s, w[k], acc);
        }
        #pragma unroll
        for (int off = 32; off > 0; off >>= 1) acc += __shfl_xor(acc, off, 64);
        const float vh = ALPHA_F * v_h + acc;
        const bool hp = (vh >= 1.0f + b_h);
        const float sh = hp ? 1.f : 0.f;
        v_h  = hp ? 0.f : vh;
        b_h  = BETA_F * b_h + sh;
        tr_h = hp ? 1.f : tr_h * DECAY_TR;
        const float apot = NU1_POST_F * sh, adep = NU1_PRE_F * tr_h;
        #pragma unroll
        for (int k = 0; k < 9; ++k) {
            const float nw = w[k] + apot * tr_in[k] - adep * s_in[k];
            w[k] = fminf(fmaxf(nw, 0.f), 1.f);   // clip [0,1]
        }
        const int par = t & 1;
        if (lane == 0) sh4[par][wv] = sh;
        __syncthreads();
        if (tid == 0)
            *(float4*)&Sf[(size_t)t * HID_D + p * 4] =
                make_float4(sh4[par][0], sh4[par][1], sh4[par][2], sh4[par][3]);
    }
}

// ------------------------- Phase 2a: bit-pack S ----------------------------
__global__ void pack_kernel(const float* __restrict__ Sf, const int* __restrict__ Tp,
                            unsigned long long* __restrict__ Sb)
{
    const int T = Tp[0];
    const int t = blockIdx.x;
    if (t >= T) return;
    const int lane = threadIdx.x & 63, wv = threadIdx.x >> 6;
    #pragma unroll
    for (int q = 0; q < 4; ++q) {
        const int word = wv * 4 + q;                  // 0..15
        const float s = Sf[(size_t)t * HID_D + word * 64 + lane];
        const unsigned long long m = __ballot(s > 0.5f);
        if (lane == 0) Sb[(size_t)t * 16 + word] = m;
    }
}

// ------------------------- Phase 2b: Gram G = S S^T ------------------------
__global__ void gram_kernel(const unsigned long long* __restrict__ Sb,
                            const int* __restrict__ Tp, float* __restrict__ G)
{
    const int T = Tp[0];
    if ((int)blockIdx.x > (int)blockIdx.y) return;    // need u < t only
    const int tid = threadIdx.x;
    __shared__ unsigned long long tR[16][17], uR[16][17]; // +1 pad: kill 16-way conflicts
    {
        const int r = tid >> 4, w = tid & 15;
        const int trow = blockIdx.y * 16 + r, urow = blockIdx.x * 16 + r;
        tR[r][w] = (trow < T) ? Sb[(size_t)trow * 16 + w] : 0ULL;
        uR[r][w] = (urow < T) ? Sb[(size_t)urow * 16 + w] : 0ULL;
    }
    __syncthreads();
    const int tx = tid & 15, ty = tid >> 4;
    const int t = blockIdx.y * 16 + ty, u = blockIdx.x * 16 + tx;
    if (t < T && u < t) {
        int s = 0;
        #pragma unroll
        for (int w = 0; w < 16; ++w) s += __popcll(tR[ty][w] & uR[tx][w]);
        G[(size_t)t * TMAX + u] = (float)s;
    }
}

// ------------------ Phase 3: M_T(tau,t) = nu2*(H(t,tau)-K(t,tau)) ----------
__global__ void mt_kernel(const float* __restrict__ G, const int* __restrict__ Tp,
                          float* __restrict__ MT)
{
    const int T = Tp[0];
    const int t = blockIdx.x * 64 + threadIdx.x;       // column of M_T, 0..511
    if (t >= TMAX) return;
    const int zstart = (t < T) ? t : 0;                // zero tau >= t (and full col if t>=T)
    for (int tau = zstart; tau < TMAX; ++tau) MT[(size_t)tau * TMAX + t] = 0.f;
    if (t >= T) return;
    const float* Gr = G + (size_t)t * TMAX;
    float kv = 0.f;                                    // K suffix: K = G + d*K
    for (int tau = t - 1; tau >= 0; --tau) {
        kv = fmaf(DECAY_PM, kv, Gr[tau]);
        MT[(size_t)tau * TMAX + t] = kv;
    }
    float hv = 0.f;                                    // H prefix: H = d*H + G
    for (int tau = 0; tau < t; ++tau) {
        hv = fmaf(DECAY_PM, hv, Gr[tau]);
        const float kvv = MT[(size_t)tau * TMAX + t];
        MT[(size_t)tau * TMAX + t] = NU2_F * (hv - kvv);
    }
}

// ------------------------- Phase 4: A_T = (S @ w2)^T -----------------------
__global__ __launch_bounds__(256)
void gemm_kernel(const float* __restrict__ Sf, const float* __restrict__ w2,
                 float* __restrict__ AT)
{
    const int tid = threadIdx.x;
    const int j0 = blockIdx.x * 64, t0 = blockIdx.y * 64;
    __shared__ float Ss[16][68], Ws[16][68];           // stride 68: aligned + bank-spread
    const int ti4 = tid >> 2, kq = tid & 3;            // S staging
    const int kw = tid >> 4, jq = tid & 15;            // W staging
    const int ty = tid >> 4, tx = tid & 15;            // compute 4x4 at (4ty, 4tx)
    float acc[4][4];
    #pragma unroll
    for (int i = 0; i < 4; ++i)
        #pragma unroll
        for (int jj = 0; jj < 4; ++jj) acc[i][jj] = 0.f;

    for (int k0 = 0; k0 < HID_D; k0 += 16) {
        const float4 sv  = *(const float4*)&Sf[(size_t)(t0 + ti4) * HID_D + k0 + kq * 4];
        const float4 wv4 = *(const float4*)&w2[(size_t)(k0 + kw) * OUT_D + j0 + jq * 4];
        Ss[kq * 4 + 0][ti4] = sv.x;
        Ss[kq * 4 + 1][ti4] = sv.y;
        Ss[kq * 4 + 2][ti4] = sv.z;
        Ss[kq * 4 + 3][ti4] = sv.w;
        *(float4*)&Ws[kw][jq * 4] = wv4;
        __syncthreads();
        #pragma unroll
        for (int kk = 0; kk < 16; ++kk) {
            const float4 a = *(const float4*)&Ss[kk][ty * 4];
            const float4 b = *(const float4*)&Ws[kk][tx * 4];
            acc[0][0] = fmaf(a.x, b.x, acc[0][0]); acc[0][1] = fmaf(a.x, b.y, acc[0][1]);
            acc[0][2] = fmaf(a.x, b.z, acc[0][2]); acc[0][3] = fmaf(a.x, b.w, acc[0][3]);
            acc[1][0] = fmaf(a.y, b.x, acc[1][0]); acc[1][1] = fmaf(a.y, b.y, acc[1][1]);
            acc[1][2] = fmaf(a.y, b.z, acc[1][2]); acc[1][3] = fmaf(a.y, b.w, acc[1][3]);
            acc[2][0] = fmaf(a.z, b.x, acc[2][0]); acc[2][1] = fmaf(a.z, b.y, acc[2][1]);
            acc[2][2] = fmaf(a.z, b.z, acc[2][2]); acc[2][3] = fmaf(a.z, b.w, acc[2][3]);
            acc[3][0] = fmaf(a.w, b.x, acc[3][0]); acc[3][1] = fmaf(a.w, b.y, acc[3][1]);
            acc[3][2] = fmaf(a.w, b.z, acc[3][2]); acc[3][3] = fmaf(a.w, b.w, acc[3][3]);
        }
        __syncthreads();
    }
    #pragma unroll
    for (int jj = 0; jj < 4; ++jj)
        *(float4*)&AT[(size_t)(j0 + tx * 4 + jj) * TMAX + t0 + ty * 4] =
            make_float4(acc[0][jj], acc[1][jj], acc[2][jj], acc[3][jj]);
}

// ------------------------- Phase 5: output recurrence ----------------------
__global__ __launch_bounds__(512, 2)
void out_kernel(const float* __restrict__ AT, const float* __restrict__ MT,
                const int* __restrict__ Tp, float* __restrict__ out)
{
    const int T = Tp[0];
    const int tid = threadIdx.x, lane = tid & 63, wv = tid >> 6;
    const int j = blockIdx.x * 8 + wv;                // this wave's output column
    __shared__ float ml[2][TMAX];                     // double-buffered M_T row

    float hsum[NW];                                   // hsum[c] on lane l: running
    #pragma unroll                                    //  sum_{tau<t} M(64c+l,tau)so(tau)
    for (int k = 0; k < NW; ++k) hsum[k] = 0.f;
    float v = REST_F;

    ml[0][tid] = MT[tid];                             // stage row 0 (512 threads)
    __syncthreads();

    #pragma unroll
    for (int c = 0; c < NW; ++c) {
        if (64 * c >= T) break;
        const float av = AT[(size_t)j * TMAX + 64 * c + lane];  // A(64c+lane, j)
        for (int tt = 0; tt < 64; ++tt) {
            const int t = 64 * c + tt;
            if (t >= T) break;
            const int tn = (t + 1 < T) ? (t + 1) : (T - 1);
            const float stg = MT[(size_t)tn * TMAX + tid];      // prefetch next row
            const float ival = __shfl(av + hsum[c], tt, 64);    // i_out(t,j), all lanes
            const float vd = DECAY_V * (v - REST_F) + REST_F + ival;
            const bool sp = (vd >= THRESH_F);                   // wave-uniform
            v = sp ? RESET_F : vd;
            if (lane == 0) out[(size_t)t * OUT_D + j] = sp ? 1.f : 0.f;
            if (sp) {                                           // rank-1 update
                const float* row = ml[t & 1];
                #pragma unroll
                for (int k = 0; k < NW; ++k) hsum[k] += row[64 * k + lane];
            }
            ml[(t + 1) & 1][tid] = stg;
            __syncthreads();
        }
    }
}

extern "C" void kernel_launch(void* const* d_in, const int* in_sizes, int n_in,
                              void* d_out, int out_size, void* d_ws, size_t ws_size,
                              hipStream_t stream) {
    const float* x  = (const float*)d_in[0];
    const float* w1 = (const float*)d_in[1];
    const float* w2 = (const float*)d_in[2];
    const int*   Tp = (const int*)d_in[3];
    float* out = (float*)d_out;
    char* ws = (char*)d_ws;
    // workspace layout (8.45 MB total)
    unsigned long long* Sb = (unsigned long long*)(ws);               // 64 KB
    float* G  = (float*)(ws + 65536);                                 // 1 MB
    float* MT = (float*)(ws + 65536 + 1048576);                       // 1 MB
    float* AT = (float*)(ws + 65536 + 2 * 1048576);                   // 4 MB
    float* Sf = (float*)(ws + 65536 + 2 * 1048576 + 4194304);         // 2 MB

    hipLaunchKernelGGL(hidden_kernel, dim3(256), dim3(256), 0, stream, x, w1, Tp, Sf);
    hipLaunchKernelGGL(pack_kernel,   dim3(TMAX), dim3(256), 0, stream, Sf, Tp, Sb);
    hipLaunchKernelGGL(gram_kernel,   dim3(32, 32), dim3(256), 0, stream, Sb, Tp, G);
    hipLaunchKernelGGL(mt_kernel,     dim3(8), dim3(64), 0, stream, G, Tp, MT);
    hipLaunchKernelGGL(gemm_kernel,   dim3(32, 8), dim3(256), 0, stream, Sf, w2, AT);
    hipLaunchKernelGGL(out_kernel,    dim3(256), dim3(512), 0, stream, AT, MT, Tp, out);
}

// Round 3
// 402.127 us; speedup vs baseline: 1.8353x; 1.8353x over previous
//
#include <hip/hip_runtime.h>
#include <stdint.h>

// ---------------------------------------------------------------------------
// Phased SNN:
//   1) hidden raster S   (sequential, DPP wave-reduce, no barriers)
//   2) pack S bits + zero tail rows of Sf
//   3) Gram G = S S^T    (popcount, exact)
//   4) M_T via wave-parallel decay scans (Kogge-Stone with multiplier)
//   5) A_T = (S @ w2_0)^T  f32 GEMM, K-split x2 across blocks
//   6) output LIF recurrence, barrier-free, register-resident M_T rows
// Valid because w2 is never clipped -> its evolution is linear in spikes.
// ---------------------------------------------------------------------------

#define DECAY_V  0.90483741803595952f   // exp(-1/10)
#define DECAY_TR 0.95122942450071403f   // exp(-1/20)
#define DECAY_PM 0.95122942450071403f   // exp(-1/20)
#define REST_F   (-70.0f)
#define RESET_F  (-65.0f)
#define THRESH_F (-55.0f)
#define ALPHA_F  (0.95f)
#define BETA_F   (0.8f)
#define NU1_PRE_F  (0.001f)
#define NU1_POST_F (0.01f)
#define NU2_F      (0.0001f)
#define GAIN_F     (20.0f)
#define LOG2D    (-0.072134752044448170f)  // log2(exp(-1/20))

static constexpr int IN_D  = 544;
static constexpr int HID_D = 1024;
static constexpr int OUT_D = 2048;
static constexpr int TMAX  = 512;

// d^1,2,4,8,16,32 (exp(-k/20))
#define DP1  0.95122942450071403f
#define DP2  0.90483741803595957f
#define DP4  0.81873075307798186f
#define DP8  0.67032004603563930f
#define DP16 0.44932896411722159f
#define DP32 0.20189651799465541f

__device__ __forceinline__ float rdlane(float x, int l) {
    return __builtin_bit_cast(float,
        __builtin_amdgcn_readlane(__builtin_bit_cast(int, x), l));
}

template <int CTRL>
__device__ __forceinline__ float dpp_add(float x) {
    int y = __builtin_amdgcn_update_dpp(0, __builtin_bit_cast(int, x),
                                        CTRL, 0xF, 0xF, true);
    return x + __builtin_bit_cast(float, y);
}

// rocPRIM-style wave64 sum; total lands in lane 63.
__device__ __forceinline__ float wave_sum64(float x) {
    x = dpp_add<0xB1>(x);   // quad_perm [1,0,3,2]
    x = dpp_add<0x4E>(x);   // quad_perm [2,3,0,1]
    x = dpp_add<0x114>(x);  // row_shr:4
    x = dpp_add<0x118>(x);  // row_shr:8
    x = dpp_add<0x142>(x);  // row_bcast:15
    x = dpp_add<0x143>(x);  // row_bcast:31
    return rdlane(x, 63);
}

// ------------------------- Phase 1: hidden raster --------------------------
__global__ __launch_bounds__(256)
void hidden_kernel(const float* __restrict__ x, const float* __restrict__ w1,
                   const int* __restrict__ Tp, float* __restrict__ Sf)
{
    const int T = Tp[0];
    const int tid = threadIdx.x, lane = tid & 63, wv = tid >> 6;
    const int col = blockIdx.x * 4 + wv;
    const float c0 = REST_F * (1.0f - DECAY_V);

    float w[9], vi[9], tr[9], cadd[9];
    #pragma unroll
    for (int k = 0; k < 9; ++k) {
        const int i = lane + 64 * k;
        const bool ok = (i < IN_D);
        w[k]    = ok ? w1[(size_t)i * HID_D + col] : 0.f;
        cadd[k] = c0 + (ok ? x[i] * GAIN_F : 0.f);
        vi[k]   = REST_F;
        tr[k]   = 0.f;
    }
    float v_h = 0.f, b_h = 0.f, tr_h = 0.f;

    for (int t = 0; t < T; ++t) {
        float acc = 0.f, s[9];
        #pragma unroll
        for (int k = 0; k < 9; ++k) {
            const float vv = fmaf(DECAY_V, vi[k], cadd[k]);
            const bool sp = (vv >= THRESH_F);
            vi[k] = sp ? RESET_F : vv;
            tr[k] = sp ? 1.f : tr[k] * DECAY_TR;
            s[k]  = sp ? 1.f : 0.f;
            acc   = fmaf(s[k], w[k], acc);
        }
        const float tot = wave_sum64(acc);
        const float vh2 = fmaf(ALPHA_F, v_h, tot);
        const bool hp = (vh2 >= 1.0f + b_h);
        const float sh = hp ? 1.f : 0.f;
        v_h  = hp ? 0.f : vh2;
        b_h  = fmaf(BETA_F, b_h, sh);
        tr_h = hp ? 1.f : tr_h * DECAY_TR;
        const float apot = hp ? NU1_POST_F : 0.f;
        const float adep = NU1_PRE_F * tr_h;
        #pragma unroll
        for (int k = 0; k < 9; ++k) {
            const float a = fmaf(apot, tr[k], w[k]);
            const float nw = fmaf(-adep, s[k], a);
            w[k] = __builtin_amdgcn_fmed3f(nw, 0.f, 1.f);
        }
        if (lane == 0) Sf[(size_t)t * HID_D + col] = sh;
    }
}

// ---------------- Phase 2: bit-pack S (+ zero tail rows) -------------------
__global__ void pack_kernel(float* __restrict__ Sf, const int* __restrict__ Tp,
                            unsigned long long* __restrict__ Sb)
{
    const int T = Tp[0];
    const int t = blockIdx.x;
    const int lane = threadIdx.x & 63, wv = threadIdx.x >> 6;
    if (t >= T) {   // zero garbage rows so gemm/AT tail is clean
        ((float4*)(Sf + (size_t)t * HID_D))[threadIdx.x] = make_float4(0.f, 0.f, 0.f, 0.f);
        return;
    }
    #pragma unroll
    for (int q = 0; q < 4; ++q) {
        const int word = wv * 4 + q;
        const float s = Sf[(size_t)t * HID_D + word * 64 + lane];
        const unsigned long long m = __ballot(s > 0.5f);
        if (lane == 0) Sb[(size_t)t * 16 + word] = m;
    }
}

// ------------------------- Phase 3: Gram G = S S^T -------------------------
__global__ void gram_kernel(const unsigned long long* __restrict__ Sb,
                            const int* __restrict__ Tp, float* __restrict__ G)
{
    const int T = Tp[0];
    if ((int)blockIdx.x > (int)blockIdx.y) return;
    const int tid = threadIdx.x;
    __shared__ unsigned long long tR[16][17], uR[16][17];
    {
        const int r = tid >> 4, w = tid & 15;
        const int trow = blockIdx.y * 16 + r, urow = blockIdx.x * 16 + r;
        tR[r][w] = (trow < T) ? Sb[(size_t)trow * 16 + w] : 0ULL;
        uR[r][w] = (urow < T) ? Sb[(size_t)urow * 16 + w] : 0ULL;
    }
    __syncthreads();
    const int tx = tid & 15, ty = tid >> 4;
    const int t = blockIdx.y * 16 + ty, u = blockIdx.x * 16 + tx;
    if (t < T && u < t) {
        int s = 0;
        #pragma unroll
        for (int w = 0; w < 16; ++w) s += __popcll(tR[ty][w] & uR[tx][w]);
        G[(size_t)t * TMAX + u] = (float)s;
    }
}

// -------------- Phase 4: M_T columns via parallel decay scans --------------
__global__ __launch_bounds__(256)
void mt_kernel(const float* __restrict__ G, const int* __restrict__ Tp,
               float* __restrict__ MT)
{
    const int T = Tp[0];
    const int lane = threadIdx.x & 63;
    const int t = blockIdx.x * 4 + (threadIdx.x >> 6);   // wave's column
    if (t >= T) return;
    const float* Gr = G + (size_t)t * TMAX;
    const float dl1  = exp2f((float)(lane + 1) * LOG2D);  // d^(lane+1)
    const float d64l = exp2f((float)(64 - lane) * LOG2D); // d^(64-lane)

    float g[8], kk[8];
    #pragma unroll
    for (int c = 0; c < 8; ++c) {
        const int tau = 64 * c + lane;
        g[c] = (tau < t) ? Gr[tau] : 0.f;
    }
    // backward inclusive decay scan K (high chunk -> low)
    float kc = 0.f;
    #pragma unroll
    for (int c = 7; c >= 0; --c) {
        float k = g[c], u;
        u = __shfl_down(k, 1, 64);  if (lane < 63) k = fmaf(DP1, u, k);
        u = __shfl_down(k, 2, 64);  if (lane < 62) k = fmaf(DP2, u, k);
        u = __shfl_down(k, 4, 64);  if (lane < 60) k = fmaf(DP4, u, k);
        u = __shfl_down(k, 8, 64);  if (lane < 56) k = fmaf(DP8, u, k);
        u = __shfl_down(k, 16, 64); if (lane < 48) k = fmaf(DP16, u, k);
        u = __shfl_down(k, 32, 64); if (lane < 32) k = fmaf(DP32, u, k);
        k = fmaf(d64l, kc, k);
        kk[c] = k;
        kc = rdlane(k, 0);
    }
    // forward inclusive decay scan H + write nu2*(H-K)
    float hc = 0.f;
    #pragma unroll
    for (int c = 0; c < 8; ++c) {
        float h = g[c], u;
        u = __shfl_up(h, 1, 64);  if (lane >= 1)  h = fmaf(DP1, u, h);
        u = __shfl_up(h, 2, 64);  if (lane >= 2)  h = fmaf(DP2, u, h);
        u = __shfl_up(h, 4, 64);  if (lane >= 4)  h = fmaf(DP4, u, h);
        u = __shfl_up(h, 8, 64);  if (lane >= 8)  h = fmaf(DP8, u, h);
        u = __shfl_up(h, 16, 64); if (lane >= 16) h = fmaf(DP16, u, h);
        u = __shfl_up(h, 32, 64); if (lane >= 32) h = fmaf(DP32, u, h);
        h = fmaf(dl1, hc, h);
        const int tau = 64 * c + lane;
        MT[(size_t)tau * TMAX + t] = (tau < t) ? (NU2_F * (h - kk[c])) : 0.f;
        hc = rdlane(h, 63);
    }
}

// ---------------- Phase 5: A_T = (S @ w2)^T, K-split GEMM ------------------
__global__ __launch_bounds__(256)
void gemm_kernel(const float* __restrict__ Sf, const float* __restrict__ w2,
                 float* __restrict__ AT, int klen)
{
    const int j0 = blockIdx.x * 128;
    const int t0 = blockIdx.y * 64;
    const int kbase = blockIdx.z * 512;
    float* ATp = AT + (size_t)blockIdx.z * OUT_D * TMAX;
    __shared__ float Ss[16][68];    // [k][t], 16B-aligned rows
    __shared__ float Ws[16][192];   // [k][j] stride-12 oct swizzle (2-way max)
    const int tid = threadIdx.x;
    const int sr = tid >> 2, sq = tid & 3;     // S staging: row t0+sr, k-quad sq
    const int wq2 = tid & 31, wr2 = tid >> 5;  // W staging: quad wq2, k rows wr2/wr2+8
    const int wcol = (wq2 >> 1) * 12 + (wq2 & 1) * 4;
    const int tj = tid & 15, tt = tid >> 4;    // compute: 8 j x 4 t
    const int tjc = tj * 12;

    float acc[4][8];
    #pragma unroll
    for (int a = 0; a < 4; ++a)
        #pragma unroll
        for (int b = 0; b < 8; ++b) acc[a][b] = 0.f;

    for (int k0 = 0; k0 < klen; k0 += 16) {
        const float4 sv = *(const float4*)&Sf[(size_t)(t0 + sr) * HID_D + kbase + k0 + sq * 4];
        const float4 wa = *(const float4*)&w2[(size_t)(kbase + k0 + wr2) * OUT_D + j0 + wq2 * 4];
        const float4 wb = *(const float4*)&w2[(size_t)(kbase + k0 + wr2 + 8) * OUT_D + j0 + wq2 * 4];
        __syncthreads();
        Ss[sq * 4 + 0][sr] = sv.x;
        Ss[sq * 4 + 1][sr] = sv.y;
        Ss[sq * 4 + 2][sr] = sv.z;
        Ss[sq * 4 + 3][sr] = sv.w;
        *(float4*)&Ws[wr2][wcol] = wa;
        *(float4*)&Ws[wr2 + 8][wcol] = wb;
        __syncthreads();
        #pragma unroll
        for (int kk = 0; kk < 16; ++kk) {
            const float4 a4 = *(const float4*)&Ss[kk][tt * 4];
            const float4 b0 = *(const float4*)&Ws[kk][tjc];
            const float4 b1 = *(const float4*)&Ws[kk][tjc + 4];
            const float aa[4] = {a4.x, a4.y, a4.z, a4.w};
            const float bb[8] = {b0.x, b0.y, b0.z, b0.w, b1.x, b1.y, b1.z, b1.w};
            #pragma unroll
            for (int ti = 0; ti < 4; ++ti)
                #pragma unroll
                for (int jj = 0; jj < 8; ++jj)
                    acc[ti][jj] = fmaf(aa[ti], bb[jj], acc[ti][jj]);
        }
    }
    #pragma unroll
    for (int jj = 0; jj < 8; ++jj)
        *(float4*)&ATp[(size_t)(j0 + tj * 8 + jj) * TMAX + t0 + tt * 4] =
            make_float4(acc[0][jj], acc[1][jj], acc[2][jj], acc[3][jj]);
}

// ------------------- Phase 6: output recurrence (no barriers) --------------
__device__ __forceinline__ void rload(float (&R)[8], const float* __restrict__ MT,
                                      int t, int lane)
{
    #pragma unroll
    for (int k = 0; k < 8; ++k) R[k] = MT[(size_t)t * TMAX + 64 * k + lane];
}

__device__ __forceinline__ void ostep(int C, int t, int tt, const float (&R)[8],
                                      const float (&av)[4], float (&hs)[4][8],
                                      float (&v)[4], float* __restrict__ out,
                                      int j, int lane)
{
    float so[4];
    #pragma unroll
    for (int q = 0; q < 4; ++q) {
        const float val = av[q] + hs[q][C];
        const float iv = rdlane(val, tt);
        const float vd = fmaf(DECAY_V, v[q], REST_F * (1.0f - DECAY_V)) + iv;
        const bool sp = (vd >= THRESH_F);
        v[q] = sp ? RESET_F : vd;
        so[q] = sp ? 1.f : 0.f;
    }
    if (lane == 0)
        *(float4*)&out[(size_t)t * OUT_D + j] = make_float4(so[0], so[1], so[2], so[3]);
    #pragma unroll
    for (int q = 0; q < 4; ++q)
        #pragma unroll
        for (int k = 0; k < 8; ++k)
            hs[q][k] = fmaf(so[q], R[k], hs[q][k]);
}

__global__ __launch_bounds__(256)
void out_kernel(const float* __restrict__ AT, const float* __restrict__ MT,
                const int* __restrict__ Tp, float* __restrict__ out, int nparts)
{
    const int T = Tp[0];
    const int lane = threadIdx.x & 63;
    const int wid = blockIdx.x * 4 + (threadIdx.x >> 6);
    const int j = wid * 4;

    float hs[4][8];
    #pragma unroll
    for (int q = 0; q < 4; ++q)
        #pragma unroll
        for (int k = 0; k < 8; ++k) hs[q][k] = 0.f;
    float v[4] = {REST_F, REST_F, REST_F, REST_F};

    float rA[8], rB[8];
    rload(rA, MT, 0, lane);
    if (T > 1) rload(rB, MT, 1, lane);

    #pragma unroll
    for (int c = 0; c < 8; ++c) {
        if (64 * c < T) {
            float av[4];
            #pragma unroll
            for (int q = 0; q < 4; ++q) {
                float a = AT[(size_t)(j + q) * TMAX + 64 * c + lane];
                if (nparts == 2)
                    a += AT[(size_t)(OUT_D + j + q) * TMAX + 64 * c + lane];
                av[q] = a;
            }
            for (int t2 = 0; t2 < 64; t2 += 2) {
                const int ta = 64 * c + t2;
                if (ta < T) {
                    ostep(c, ta, t2, rA, av, hs, v, out, j, lane);
                    if (ta + 2 < T) rload(rA, MT, ta + 2, lane);
                }
                const int tb = ta + 1;
                if (tb < T) {
                    ostep(c, tb, t2 + 1, rB, av, hs, v, out, j, lane);
                    if (tb + 2 < T) rload(rB, MT, tb + 2, lane);
                }
            }
        }
    }
}

extern "C" void kernel_launch(void* const* d_in, const int* in_sizes, int n_in,
                              void* d_out, int out_size, void* d_ws, size_t ws_size,
                              hipStream_t stream) {
    const float* x  = (const float*)d_in[0];
    const float* w1 = (const float*)d_in[1];
    const float* w2 = (const float*)d_in[2];
    const int*   Tp = (const int*)d_in[3];
    float* out = (float*)d_out;
    char* ws = (char*)d_ws;
    // layout: Sb 64K | G 1M | MT 1M | Sf 2M | AT 4M (or 8M if K-split)
    unsigned long long* Sb = (unsigned long long*)(ws);
    float* G  = (float*)(ws + 65536);
    float* MT = (float*)(ws + 65536 + 1048576);
    float* Sf = (float*)(ws + 65536 + 2 * 1048576);
    float* AT = (float*)(ws + 65536 + 2 * 1048576 + 2097152);
    const size_t need2 = 65536 + 2 * 1048576 + 2097152 + 2 * 4194304;
    const int nparts = (ws_size >= need2) ? 2 : 1;
    const int klen = (nparts == 2) ? 512 : 1024;

    hipLaunchKernelGGL(hidden_kernel, dim3(256), dim3(256), 0, stream, x, w1, Tp, Sf);
    hipLaunchKernelGGL(pack_kernel,   dim3(TMAX), dim3(256), 0, stream, Sf, Tp, Sb);
    hipLaunchKernelGGL(gram_kernel,   dim3(32, 32), dim3(256), 0, stream, Sb, Tp, G);
    hipLaunchKernelGGL(mt_kernel,     dim3(128), dim3(256), 0, stream, G, Tp, MT);
    hipLaunchKernelGGL(gemm_kernel,   dim3(16, 8, nparts), dim3(256), 0, stream,
                       Sf, w2, AT, klen);
    hipLaunchKernelGGL(out_kernel,    dim3(128), dim3(256), 0, stream, AT, MT, Tp, out, nparts);
}